// Round 9
// baseline (345.469 us; speedup 1.0000x reference)
//
#include <hip/hip_runtime.h>
#include <stdint.h>

#define Bsz 16384
#define K1 1024
#define N1 1536
#define K2 512
#define N2 512

typedef __bf16 bf16x8 __attribute__((ext_vector_type(8)));
typedef float f32x4 __attribute__((ext_vector_type(4)));

__device__ __forceinline__ unsigned short f2bf(float f) {
    union { float f; unsigned int u; } v; v.f = f;
    unsigned int u = v.u;
    return (unsigned short)((u + 0x7fffu + ((u >> 16) & 1u)) >> 16);
}
__device__ __forceinline__ float bf2f(unsigned short s) {
    union { float f; unsigned int u; } v; v.u = ((unsigned int)s) << 16;
    return v.f;
}
__device__ __forceinline__ float sigm(float x) { return 1.0f / (1.0f + __expf(-x)); }

// ============ weight/bias prep (verified rounds 3/4/5) ============
// W1 [1536][1024] bf16, interleaved cols: n = g*512 + j*2 + part (g:0=r,1=z,2=h1)
//   k<512 multiplies [x_re|h_re]; k>=512 multiplies [x_im|h_im]
//   part0: {wre, -wim}; part1: {wim, wre}
// W2 [512][512] bf16, cols n2 = j*2+part; rows k2<256 -> rh_re, else rh_im.
// bias1[1536] f32, same interleaved order.
__global__ void build_weights(
    const float* __restrict__ wr_re, const float* __restrict__ wr_im,
    const float* __restrict__ wz_re, const float* __restrict__ wz_im,
    const float* __restrict__ wh_re, const float* __restrict__ wh_im,
    const float* __restrict__ ur_re, const float* __restrict__ ur_im,
    const float* __restrict__ uz_re, const float* __restrict__ uz_im,
    const float* __restrict__ uh_re, const float* __restrict__ uh_im,
    const float* __restrict__ br_re, const float* __restrict__ br_im,
    const float* __restrict__ bz_re, const float* __restrict__ bz_im,
    const float* __restrict__ bh_re, const float* __restrict__ bh_im,
    unsigned short* __restrict__ W1, unsigned short* __restrict__ W2,
    float* __restrict__ bias1) {
    int idx = blockIdx.x * blockDim.x + threadIdx.x;
    if (idx < N1 * K1) {
        int n = idx / K1, k = idx % K1;
        int g = n >> 9, q = n & 511, j = q >> 1, part = q & 1;
        bool second = (k >= 512);
        int kk = k & 511;
        const float *Wre, *Wim, *Ure, *Uim;
        if (g == 0)      { Wre = wr_re; Wim = wr_im; Ure = ur_re; Uim = ur_im; }
        else if (g == 1) { Wre = wz_re; Wim = wz_im; Ure = uz_re; Uim = uz_im; }
        else             { Wre = wh_re; Wim = wh_im; Ure = uh_re; Uim = uh_im; }
        float wre, wim;
        if (g < 2) {
            wre = Wre[j * 512 + kk];
            wim = Wim[j * 512 + kk];
            if (kk >= 256) { wre += Ure[j * 256 + kk - 256]; wim += Uim[j * 256 + kk - 256]; }
        } else {
            if (kk < 256) { wre = Wre[j * 512 + kk];       wim = Wim[j * 512 + kk]; }
            else          { wre = Ure[j * 256 + kk - 256]; wim = Uim[j * 256 + kk - 256]; }
        }
        float val = (part == 0) ? (second ? -wim : wre) : (second ? wre : wim);
        W1[idx] = f2bf(val);
        return;
    }
    int i2 = idx - N1 * K1;
    if (i2 < N2 * K2) {
        int n2 = i2 / K2, k2 = i2 % K2;
        int j = n2 >> 1, part = n2 & 1;
        bool second = (k2 >= 256);
        int kk = k2 & 255;
        float wre = wh_re[j * 512 + 256 + kk];
        float wim = wh_im[j * 512 + 256 + kk];
        float val = (part == 0) ? (second ? -wim : wre) : (second ? wre : wim);
        W2[i2] = f2bf(val);
        return;
    }
    int i3 = i2 - N2 * K2;
    if (i3 < N1) {
        int g = i3 >> 9, q = i3 & 511, j = q >> 1, part = q & 1;
        const float* re = (g == 0) ? br_re : ((g == 1) ? bz_re : bh_re);
        const float* im = (g == 0) ? br_im : ((g == 1) ? bz_im : bh_im);
        bias1[i3] = part ? (re[j] + im[j]) : (re[j] - im[j]);
    }
}

// ============ A builder: A = [x_re|h_re|x_im|h_im] bf16 [B, 1024] ============
__global__ void build_a(const float* __restrict__ xr, const float* __restrict__ hr,
                        const float* __restrict__ xi, const float* __restrict__ hi,
                        unsigned short* __restrict__ a) {
    int idx = blockIdx.x * blockDim.x + threadIdx.x;
    if (idx >= Bsz * K1 / 4) return;
    int t = idx * 4;
    int b = t >> 10;
    int k = t & 1023;
    const float* src;
    int off;
    if (k < 256)      { src = xr; off = b * 256 + k; }
    else if (k < 512) { src = hr; off = b * 256 + k - 256; }
    else if (k < 768) { src = xi; off = b * 256 + k - 512; }
    else              { src = hi; off = b * 256 + k - 768; }
    f32x4 v = *(const f32x4*)(src + off);
    ushort4 o;
    o.x = f2bf(v[0]); o.y = f2bf(v[1]); o.z = f2bf(v[2]); o.w = f2bf(v[3]);
    *(ushort4*)(a + t) = o;
}

// ============ GEMM core: C = A[M,K] * Bm[N,K]^T, fused epilogues ============
// 128x128 tile, BK=32, 256 thr (4 waves 2x2), mfma_f32_16x16x32_bf16.
// A ONLY in LDS (8KB, paired-line swizzle, 0 conflicts — verified r5).
// W (B operand) register-direct from global/L2 per k-step (math verified r4):
//   3MB W1 is L2-resident; B loads have no barrier dependency -> pipelined.
// MODE 1 epilogue: g==0: rh->A2 bf16; g==1: z preact->C1z bf16; g==2: h1->C1h bf16
// MODE 2 epilogue: z/tanh/h_new -> out.
template<int K, int NBX, int MODE>
__global__ __launch_bounds__(256, 4)
void gemm_fused(const unsigned short* __restrict__ A,
                const unsigned short* __restrict__ Bm,
                const float* __restrict__ bias,
                const float* __restrict__ hre_g,
                const float* __restrict__ him_g,
                unsigned short* __restrict__ c1z,
                unsigned short* __restrict__ c1h,
                unsigned short* __restrict__ A2,
                float* __restrict__ outp) {
    __shared__ __align__(16) unsigned short sA[128 * 32];   // 8KB, 64 lines
    const int tid  = threadIdx.x;
    const int lane = tid & 63;
    const int wid  = tid >> 6;

    // XCD-aware bijective swizzle (gridDim.x % 8 == 0 for all launches)
    const int nwg = gridDim.x;
    const int cpx = nwg >> 3;
    const int wgid = (blockIdx.x & 7) * cpx + (blockIdx.x >> 3);
    const int bx = wgid % NBX;
    const int by = wgid / NBX;
    const int rowA0 = by * 128;
    const int col0  = bx * 128;
    const int wm = (wid >> 1) * 64;
    const int wn = (wid & 1) * 64;

    f32x4 acc[4][4];
#pragma unroll
    for (int i = 0; i < 4; i++)
#pragma unroll
        for (int j = 0; j < 4; j++) acc[i][j] = {0.f, 0.f, 0.f, 0.f};

    // staging decomposition: lane -> (local line, slot)
    const int ll   = lane >> 3;          // 0..7 local line within an issue
    const int sl   = lane & 7;           // LDS slot within line
    // fragment indices
    const int fr = lane & 15;
    const int fc = lane >> 4;            // k-chunk 0..3

    // invariant staging addresses (only k0 varies)
    const int Lb0 = wid * 16;
    const int L0  = Lb0 + ll;
    const int sidx0 = sl ^ (L0 & 7);
    const int grow0 = 2 * L0 + (sidx0 >> 2);
    const int Lb1 = wid * 16 + 8;
    const int L1  = Lb1 + ll;
    const int sidx1 = sl ^ (L1 & 7);
    const int grow1 = 2 * L1 + (sidx1 >> 2);
    // W fragment base (per lane): row = col0+wn+n*16+fr, byte col = fc*16
    const unsigned short* Wb = Bm + (size_t)(col0 + wn + fr) * K + fc * 8;

    for (int k0 = 0; k0 < K; k0 += 32) {
        // B fragments: global/L2, no barrier dependency
        bf16x8 bv[4];
#pragma unroll
        for (int n = 0; n < 4; n++)
            bv[n] = *(const bf16x8*)(Wb + (size_t)n * 16 * K + k0);

        __syncthreads();   // previous compute done before overwrite
        {
            const unsigned short* gp = A + (size_t)(rowA0 + grow0) * K + k0 + (sidx0 & 3) * 8;
            unsigned short* lp = sA + Lb0 * 64 + lane * 8;
            __builtin_amdgcn_global_load_lds((const __attribute__((address_space(1))) void*)gp,
                                             (__attribute__((address_space(3))) void*)lp,
                                             16, 0, 0);
        }
        {
            const unsigned short* gp = A + (size_t)(rowA0 + grow1) * K + k0 + (sidx1 & 3) * 8;
            unsigned short* lp = sA + Lb1 * 64 + lane * 8;
            __builtin_amdgcn_global_load_lds((const __attribute__((address_space(1))) void*)gp,
                                             (__attribute__((address_space(3))) void*)lp,
                                             16, 0, 0);
        }
        __syncthreads();   // staging complete

        bf16x8 af[4];
#pragma unroll
        for (int m = 0; m < 4; m++) {
            int r = wm + m * 16 + fr;
            int L = r >> 1;
            int slot = ((r & 1) * 4 + fc) ^ (L & 7);
            af[m] = *(const bf16x8*)(sA + L * 64 + slot * 8);
        }
#pragma unroll
        for (int m = 0; m < 4; m++)
#pragma unroll
            for (int n = 0; n < 4; n++)
                acc[m][n] = __builtin_amdgcn_mfma_f32_16x16x32_bf16(af[m], bv[n], acc[m][n], 0, 0, 0);
    }

    // epilogue: C/D layout col=lane&15, row=(lane>>4)*4+reg  [m89/m91]
    const int crow = (lane >> 4) * 4;
    const int ccol = lane & 15;

    if constexpr (MODE == 1) {
        const int g = col0 >> 9;   // 0=r, 1=z, 2=h1 (uniform per block)
#pragma unroll
        for (int m = 0; m < 4; m++) {
#pragma unroll
            for (int n = 0; n < 4; n++) {
                int nc = col0 + wn + n * 16 + ccol;    // global col
                int qc = nc & 511;                      // within-gate col
                int jj = qc >> 1;
                int part = qc & 1;
                float bv = bias[nc];
#pragma unroll
                for (int j = 0; j < 4; j++) {
                    int gr = rowA0 + wm + m * 16 + crow + j;
                    float v = acc[m][n][j] + bv;
                    if (g == 0) {
                        float s  = sigm(v);
                        float sp = __shfl_xor(s, 1);
                        float hr = hre_g[gr * 256 + jj];
                        float hi = him_g[gr * 256 + jj];
                        // even(part0): rr=s, ri=sp -> rh_re = s*hr - sp*hi
                        // odd (part1): ri=s, rr=sp -> rh_im = s*hr + sp*hi
                        float val = part ? (s * hr + sp * hi) : (s * hr - sp * hi);
                        A2[(size_t)gr * 512 + part * 256 + jj] = f2bf(val);
                    } else if (g == 1) {
                        c1z[(size_t)gr * 512 + qc] = f2bf(v);
                    } else {
                        c1h[(size_t)gr * 512 + qc] = f2bf(v);
                    }
                }
            }
        }
    } else {
#pragma unroll
        for (int m = 0; m < 4; m++) {
#pragma unroll
            for (int n = 0; n < 4; n++) {
                int qc = col0 + wn + n * 16 + ccol;     // 0..511 interleaved
                int jj = qc >> 1;
                int part = qc & 1;
#pragma unroll
                for (int j = 0; j < 4; j++) {
                    int gr = rowA0 + wm + m * 16 + crow + j;
                    float zpre = bf2f(c1z[(size_t)gr * 512 + qc]);
                    float hpre = bf2f(c1h[(size_t)gr * 512 + qc]) + acc[m][n][j];
                    float z  = sigm(zpre);
                    float hh = tanhf(hpre);
                    float zp  = __shfl_xor(z, 1);
                    float hhp = __shfl_xor(hh, 1);
                    float hr = hre_g[gr * 256 + jj];
                    float hi = him_g[gr * 256 + jj];
                    float res;
                    if (part == 0)
                        res = (1.f - z) * hr + zp * hi + z * hh - zp * hhp;
                    else
                        res = (1.f - zp) * hi - z * hr + zp * hh + z * hhp;
                    outp[(size_t)part * (Bsz * 256) + (size_t)gr * 256 + jj] = res;
                }
            }
        }
    }
}

extern "C" void kernel_launch(void* const* d_in, const int* in_sizes, int n_in,
                              void* d_out, int out_size, void* d_ws, size_t ws_size,
                              hipStream_t stream) {
    const float* x_re = (const float*)d_in[0];
    const float* x_im = (const float*)d_in[1];
    const float* h_re = (const float*)d_in[2];
    const float* h_im = (const float*)d_in[3];
    const float* wr_w_re = (const float*)d_in[4];
    const float* wr_w_im = (const float*)d_in[5];
    const float* wr_b_re = (const float*)d_in[6];
    const float* wr_b_im = (const float*)d_in[7];
    const float* wz_w_re = (const float*)d_in[8];
    const float* wz_w_im = (const float*)d_in[9];
    const float* wz_b_re = (const float*)d_in[10];
    const float* wz_b_im = (const float*)d_in[11];
    const float* wh_w_re = (const float*)d_in[12];
    const float* wh_w_im = (const float*)d_in[13];
    const float* wh_b_re = (const float*)d_in[14];
    const float* wh_b_im = (const float*)d_in[15];
    const float* ur_w_re = (const float*)d_in[16];
    const float* ur_w_im = (const float*)d_in[17];
    const float* uz_w_re = (const float*)d_in[18];
    const float* uz_w_im = (const float*)d_in[19];
    const float* uh_w_re = (const float*)d_in[20];
    const float* uh_w_im = (const float*)d_in[21];

    // ws layout. Total 87,562,240 B.
    char* ws = (char*)d_ws;
    unsigned short* W1    = (unsigned short*)(ws);               //  3,145,728 B
    unsigned short* W2    = (unsigned short*)(ws + 3145728);     //    524,288 B
    float*          bias1 = (float*)         (ws + 3670016);     //      6,144 B
    unsigned short* A_bf  = (unsigned short*)(ws + 3676160);     // 33,554,432 B
    unsigned short* A2    = (unsigned short*)(ws + 37230592);    // 16,777,216 B
    unsigned short* C1z   = (unsigned short*)(ws + 54007808);    // 16,777,216 B
    unsigned short* C1h   = (unsigned short*)(ws + 70785024);    // 16,777,216 B

    const int prep_elems = N1 * K1 + N2 * K2 + N1;
    build_weights<<<(prep_elems + 255) / 256, 256, 0, stream>>>(
        wr_w_re, wr_w_im, wz_w_re, wz_w_im, wh_w_re, wh_w_im,
        ur_w_re, ur_w_im, uz_w_re, uz_w_im, uh_w_re, uh_w_im,
        wr_b_re, wr_b_im, wz_b_re, wz_b_im, wh_b_re, wh_b_im,
        W1, W2, bias1);

    build_a<<<(Bsz * K1 / 4 + 255) / 256, 256, 0, stream>>>(x_re, h_re, x_im, h_im, A_bf);

    gemm_fused<K1, N1 / 128, 1><<<(N1 / 128) * (Bsz / 128), 256, 0, stream>>>(
        A_bf, W1, bias1, h_re, h_im, C1z, C1h, A2, nullptr);

    gemm_fused<K2, N2 / 128, 2><<<(N2 / 128) * (Bsz / 128), 256, 0, stream>>>(
        A2, W2, nullptr, h_re, h_im, C1z, C1h, nullptr, (float*)d_out);
}

// Round 10
// 270.880 us; speedup vs baseline: 1.2754x; 1.2754x over previous
//
#include <hip/hip_runtime.h>
#include <stdint.h>

#define Bsz 16384
#define Hsz 256
#define K1 1024
#define N1 1536
#define K2 512
#define N2 512

typedef __bf16 bf16x8 __attribute__((ext_vector_type(8)));
typedef float f32x4 __attribute__((ext_vector_type(4)));

__device__ __forceinline__ unsigned short f2bf(float f) {
    union { float f; unsigned int u; } v; v.f = f;
    unsigned int u = v.u;
    return (unsigned short)((u + 0x7fffu + ((u >> 16) & 1u)) >> 16);
}
__device__ __forceinline__ float bf2f(unsigned short s) {
    union { float f; unsigned int u; } v; v.u = ((unsigned int)s) << 16;
    return v.f;
}
__device__ __forceinline__ float sigm(float x) { return 1.0f / (1.0f + __expf(-x)); }

// ---------------- weight prep (round-2 layout, verified) ----------------
// Wbig1 [1536][1024] bf16:
//   n in [0,768): re-output of gate g=n/256 (0=r,1=z,2=h1), j=n%256
//   n in [768,1536): im-output
//   k in [0,512): multiplies [x_re|h_re]; k in [512,1024): [x_im|h_im]
__global__ void build_wbig1(const float* __restrict__ wr_re, const float* __restrict__ wr_im,
                            const float* __restrict__ wz_re, const float* __restrict__ wz_im,
                            const float* __restrict__ wh_re, const float* __restrict__ wh_im,
                            const float* __restrict__ ur_re, const float* __restrict__ ur_im,
                            const float* __restrict__ uz_re, const float* __restrict__ uz_im,
                            const float* __restrict__ uh_re, const float* __restrict__ uh_im,
                            unsigned short* __restrict__ wbig) {
    int idx = blockIdx.x * blockDim.x + threadIdx.x;
    if (idx >= N1 * K1) return;
    int n = idx / K1, k = idx % K1;
    int ng = n % 768;
    int g = ng / 256;
    int j = ng % 256;
    bool im_out = (n >= 768);
    bool second = (k >= 512);
    int kk = k & 511;
    const float *Wre, *Wim, *Ure, *Uim;
    if (g == 0)      { Wre = wr_re; Wim = wr_im; Ure = ur_re; Uim = ur_im; }
    else if (g == 1) { Wre = wz_re; Wim = wz_im; Ure = uz_re; Uim = uz_im; }
    else             { Wre = wh_re; Wim = wh_im; Ure = uh_re; Uim = uh_im; }
    float wre, wim;
    if (g < 2) {
        wre = Wre[j * 512 + kk];
        wim = Wim[j * 512 + kk];
        if (kk >= 256) { wre += Ure[j * 256 + kk - 256]; wim += Uim[j * 256 + kk - 256]; }
    } else {
        if (kk < 256) { wre = Wre[j * 512 + kk];       wim = Wim[j * 512 + kk]; }
        else          { wre = Ure[j * 256 + kk - 256]; wim = Uim[j * 256 + kk - 256]; }
    }
    float val = (!im_out) ? (second ? -wim : wre) : (second ? wre : wim);
    wbig[idx] = f2bf(val);
}

// Wbig2 [512][512] bf16: rh-part of Wh (wh[:,256:512])
__global__ void build_wbig2(const float* __restrict__ wh_re, const float* __restrict__ wh_im,
                            unsigned short* __restrict__ wbig2) {
    int idx = blockIdx.x * blockDim.x + threadIdx.x;
    if (idx >= N2 * K2) return;
    int n = idx / K2, k = idx % K2;
    int j = n & 255;
    bool im_out = (n >= 256);
    bool second = (k >= 256);
    int kk = k & 255;
    float wre = wh_re[j * 512 + 256 + kk];
    float wim = wh_im[j * 512 + 256 + kk];
    float val = (!im_out) ? (second ? -wim : wre) : (second ? wre : wim);
    wbig2[idx] = f2bf(val);
}

__global__ void build_bias(const float* __restrict__ br_re, const float* __restrict__ br_im,
                           const float* __restrict__ bz_re, const float* __restrict__ bz_im,
                           const float* __restrict__ bh_re, const float* __restrict__ bh_im,
                           float* __restrict__ bias) {
    int n = blockIdx.x * blockDim.x + threadIdx.x;
    if (n >= N1) return;
    int ng = n % 768;
    int g = ng / 256;
    int j = ng % 256;
    const float* re = (g == 0) ? br_re : ((g == 1) ? bz_re : bh_re);
    const float* im = (g == 0) ? br_im : ((g == 1) ? bz_im : bh_im);
    bias[n] = (n < 768) ? (re[j] - im[j]) : (re[j] + im[j]);
}

// ---------------- A builder: A = [x_re|h_re|x_im|h_im] bf16 [B, 1024] ----------------
__global__ void build_a(const float* __restrict__ xr, const float* __restrict__ hr,
                        const float* __restrict__ xi, const float* __restrict__ hi,
                        unsigned short* __restrict__ a) {
    int idx = blockIdx.x * blockDim.x + threadIdx.x;
    if (idx >= Bsz * K1 / 4) return;
    int t = idx * 4;
    int b = t >> 10;
    int k = t & 1023;
    const float* src;
    int off;
    if (k < 256)      { src = xr; off = b * 256 + k; }
    else if (k < 512) { src = hr; off = b * 256 + k - 256; }
    else if (k < 768) { src = xi; off = b * 256 + k - 512; }
    else              { src = hi; off = b * 256 + k - 768; }
    f32x4 v = *(const f32x4*)(src + off);
    ushort4 o;
    o.x = f2bf(v[0]); o.y = f2bf(v[1]); o.z = f2bf(v[2]); o.w = f2bf(v[3]);
    *(ushort4*)(a + t) = o;
}

// ---------------- bf16 GEMM (round-2 core VERBATIM; only C store is bf16) ----------
// 128x128 tile, BK=32, 256 threads (4 waves 2x2), mfma_f32_16x16x32_bf16.
// NOTE: linear LDS layout has ~6.3M bank-conflict cycles (r2) but measured
// FASTER than every swizzled/refactored variant (r3/r5/r9). Keep it.
template<int K, bool HAS_BIAS>
__global__ __launch_bounds__(256)
void gemm_bt(const unsigned short* __restrict__ A,
             const unsigned short* __restrict__ Bm,
             const float* __restrict__ bias,
             unsigned short* __restrict__ C, int N) {
    __shared__ __align__(16) unsigned short sA[128 * 32];
    __shared__ __align__(16) unsigned short sB[128 * 32];
    const int tid  = threadIdx.x;
    const int lane = tid & 63;
    const int wid  = tid >> 6;
    const int rowA0 = blockIdx.y * 128;
    const int rowB0 = blockIdx.x * 128;
    const int wm = (wid >> 1) * 64;
    const int wn = (wid & 1) * 64;

    f32x4 acc[4][4];
#pragma unroll
    for (int i = 0; i < 4; i++)
#pragma unroll
        for (int j = 0; j < 4; j++) acc[i][j] = {0.f, 0.f, 0.f, 0.f};

    const int segRow   = lane >> 2;   // 0..15 within a 1KB segment (16 rows)
    const int segChunk = lane & 3;    // 16B chunk within 64B row
    const int fr = lane & 15;
    const int fc = lane >> 4;         // 0..3

    for (int k0 = 0; k0 < K; k0 += 32) {
        __syncthreads();   // previous compute done before overwrite
#pragma unroll
        for (int i = 0; i < 2; i++) {
            int s = wid + i * 4;                 // segment 0..7
            int r = s * 16 + segRow;             // tile row
            const unsigned short* gp = A + (size_t)(rowA0 + r) * K + k0 + segChunk * 8;
            unsigned short* lp = sA + s * 512 + lane * 8;
            __builtin_amdgcn_global_load_lds((const __attribute__((address_space(1))) void*)gp,
                                             (__attribute__((address_space(3))) void*)lp,
                                             16, 0, 0);
        }
#pragma unroll
        for (int i = 0; i < 2; i++) {
            int s = wid + i * 4;
            int r = s * 16 + segRow;
            const unsigned short* gp = Bm + (size_t)(rowB0 + r) * K + k0 + segChunk * 8;
            unsigned short* lp = sB + s * 512 + lane * 8;
            __builtin_amdgcn_global_load_lds((const __attribute__((address_space(1))) void*)gp,
                                             (__attribute__((address_space(3))) void*)lp,
                                             16, 0, 0);
        }
        __syncthreads();   // staging complete

        bf16x8 af[4], bfr[4];
#pragma unroll
        for (int m = 0; m < 4; m++) {
            int r = wm + m * 16 + fr;
            af[m] = *(const bf16x8*)(sA + r * 32 + fc * 8);
        }
#pragma unroll
        for (int n = 0; n < 4; n++) {
            int r = wn + n * 16 + fr;
            bfr[n] = *(const bf16x8*)(sB + r * 32 + fc * 8);
        }
#pragma unroll
        for (int m = 0; m < 4; m++)
#pragma unroll
            for (int n = 0; n < 4; n++)
                acc[m][n] = __builtin_amdgcn_mfma_f32_16x16x32_bf16(af[m], bfr[n], acc[m][n], 0, 0, 0);
    }

    // epilogue: C/D layout col=lane&15, row=(lane>>4)*4+reg  [m89/m91]
    const int crow = (lane >> 4) * 4;
    const int ccol = lane & 15;
#pragma unroll
    for (int m = 0; m < 4; m++) {
#pragma unroll
        for (int n = 0; n < 4; n++) {
            int gc = rowB0 + wn + n * 16 + ccol;
            float bv = HAS_BIAS ? bias[gc] : 0.f;
#pragma unroll
            for (int j = 0; j < 4; j++) {
                int gr = rowA0 + wm + m * 16 + crow + j;
                C[(size_t)gr * N + gc] = f2bf(acc[m][n][j] + bv);
            }
        }
    }
}

// ---------------- r = sigmoid, rh = r*h (complex), A2 = [rh_re|rh_im] bf16 ----------------
__global__ void make_rh(const unsigned short* __restrict__ C1, const float* __restrict__ hr,
                        const float* __restrict__ hi, unsigned short* __restrict__ A2) {
    int idx = blockIdx.x * blockDim.x + threadIdx.x;   // per 4 cols
    if (idx >= Bsz * 64) return;
    int b = idx >> 6;
    int j = (idx & 63) * 4;
    const unsigned short* c = C1 + (size_t)b * N1;
    ushort4 ar4 = *(const ushort4*)(c + j);          // r_re preact (cols 0..255)
    ushort4 ai4 = *(const ushort4*)(c + 768 + j);    // r_im preact
    f32x4 hre = *(const f32x4*)(hr + b * 256 + j);
    f32x4 him = *(const f32x4*)(hi + b * 256 + j);
    const unsigned short arr[4] = {ar4.x, ar4.y, ar4.z, ar4.w};
    const unsigned short aii[4] = {ai4.x, ai4.y, ai4.z, ai4.w};
    unsigned short tre[4], tim[4];
#pragma unroll
    for (int t = 0; t < 4; t++) {
        float rr = sigm(bf2f(arr[t]));
        float ri = sigm(bf2f(aii[t]));
        tre[t] = f2bf(rr * hre[t] - ri * him[t]);
        tim[t] = f2bf(rr * him[t] + ri * hre[t]);
    }
    ushort4 ore, oim;
    ore.x = tre[0]; ore.y = tre[1]; ore.z = tre[2]; ore.w = tre[3];
    oim.x = tim[0]; oim.y = tim[1]; oim.z = tim[2]; oim.w = tim[3];
    *(ushort4*)(A2 + (size_t)b * 512 + j)       = ore;
    *(ushort4*)(A2 + (size_t)b * 512 + 256 + j) = oim;
}

// ---------------- final: z=sigmoid, hh=tanh(h1+h2), h_new ----------------
__global__ void finalize(const unsigned short* __restrict__ C1, const unsigned short* __restrict__ C2,
                         const float* __restrict__ hr, const float* __restrict__ hi,
                         float* __restrict__ out) {
    int idx = blockIdx.x * blockDim.x + threadIdx.x;   // per 4 cols
    if (idx >= Bsz * 64) return;
    int b = idx >> 6;
    int j = (idx & 63) * 4;
    const unsigned short* c1 = C1 + (size_t)b * N1;
    const unsigned short* c2 = C2 + (size_t)b * N2;
    ushort4 zr4 = *(const ushort4*)(c1 + 256 + j);
    ushort4 zi4 = *(const ushort4*)(c1 + 1024 + j);
    ushort4 h1r = *(const ushort4*)(c1 + 512 + j);
    ushort4 h1i = *(const ushort4*)(c1 + 1280 + j);
    ushort4 h2r = *(const ushort4*)(c2 + j);
    ushort4 h2i = *(const ushort4*)(c2 + 256 + j);
    f32x4 hre = *(const f32x4*)(hr + b * 256 + j);
    f32x4 him = *(const f32x4*)(hi + b * 256 + j);
    const unsigned short zra[4] = {zr4.x, zr4.y, zr4.z, zr4.w};
    const unsigned short zia[4] = {zi4.x, zi4.y, zi4.z, zi4.w};
    const unsigned short h1ra[4] = {h1r.x, h1r.y, h1r.z, h1r.w};
    const unsigned short h1ia[4] = {h1i.x, h1i.y, h1i.z, h1i.w};
    const unsigned short h2ra[4] = {h2r.x, h2r.y, h2r.z, h2r.w};
    const unsigned short h2ia[4] = {h2i.x, h2i.y, h2i.z, h2i.w};
    f32x4 outr, outi;
#pragma unroll
    for (int t = 0; t < 4; t++) {
        float zr = sigm(bf2f(zra[t]));
        float zi = sigm(bf2f(zia[t]));
        float hhr = tanhf(bf2f(h1ra[t]) + bf2f(h2ra[t]));
        float hhi = tanhf(bf2f(h1ia[t]) + bf2f(h2ia[t]));
        outr[t] = (1.f - zr) * hre[t] + zi * him[t] + zr * hhr - zi * hhi;
        outi[t] = (1.f - zr) * him[t] - zi * hre[t] + zr * hhi + zi * hhr;
    }
    *(f32x4*)(out + (size_t)b * 256 + j)                      = outr;
    *(f32x4*)(out + (size_t)Bsz * 256 + (size_t)b * 256 + j)  = outi;
}

extern "C" void kernel_launch(void* const* d_in, const int* in_sizes, int n_in,
                              void* d_out, int out_size, void* d_ws, size_t ws_size,
                              hipStream_t stream) {
    const float* x_re = (const float*)d_in[0];
    const float* x_im = (const float*)d_in[1];
    const float* h_re = (const float*)d_in[2];
    const float* h_im = (const float*)d_in[3];
    const float* wr_w_re = (const float*)d_in[4];
    const float* wr_w_im = (const float*)d_in[5];
    const float* wr_b_re = (const float*)d_in[6];
    const float* wr_b_im = (const float*)d_in[7];
    const float* wz_w_re = (const float*)d_in[8];
    const float* wz_w_im = (const float*)d_in[9];
    const float* wz_b_re = (const float*)d_in[10];
    const float* wz_b_im = (const float*)d_in[11];
    const float* wh_w_re = (const float*)d_in[12];
    const float* wh_w_im = (const float*)d_in[13];
    const float* wh_b_re = (const float*)d_in[14];
    const float* wh_b_im = (const float*)d_in[15];
    const float* ur_w_re = (const float*)d_in[16];
    const float* ur_w_im = (const float*)d_in[17];
    const float* uz_w_re = (const float*)d_in[18];
    const float* uz_w_im = (const float*)d_in[19];
    const float* uh_w_re = (const float*)d_in[20];
    const float* uh_w_im = (const float*)d_in[21];

    // ws layout. Total 121,116,672 B.
    char* ws = (char*)d_ws;
    unsigned short* W1    = (unsigned short*)(ws);                //  3,145,728 B
    unsigned short* W2    = (unsigned short*)(ws + 3145728);      //    524,288 B
    float*          bias1 = (float*)         (ws + 3670016);      //      6,144 B
    unsigned short* A_bf  = (unsigned short*)(ws + 3676160);      // 33,554,432 B
    unsigned short* A2    = (unsigned short*)(ws + 37230592);     // 16,777,216 B
    unsigned short* C1    = (unsigned short*)(ws + 54007808);     // 50,331,648 B (bf16)
    unsigned short* C2    = (unsigned short*)(ws + 104339456);    // 16,777,216 B (bf16)

    build_wbig1<<<(N1 * K1 + 255) / 256, 256, 0, stream>>>(
        wr_w_re, wr_w_im, wz_w_re, wz_w_im, wh_w_re, wh_w_im,
        ur_w_re, ur_w_im, uz_w_re, uz_w_im, uh_w_re, uh_w_im, W1);
    build_wbig2<<<(N2 * K2 + 255) / 256, 256, 0, stream>>>(wh_w_re, wh_w_im, W2);
    build_bias<<<(N1 + 255) / 256, 256, 0, stream>>>(
        wr_b_re, wr_b_im, wz_b_re, wz_b_im, wh_b_re, wh_b_im, bias1);
    build_a<<<(Bsz * K1 / 4 + 255) / 256, 256, 0, stream>>>(x_re, h_re, x_im, h_im, A_bf);

    gemm_bt<K1, true><<<dim3(N1 / 128, Bsz / 128), 256, 0, stream>>>(A_bf, W1, bias1, C1, N1);

    make_rh<<<(Bsz * 64 + 255) / 256, 256, 0, stream>>>(C1, h_re, h_im, A2);

    gemm_bt<K2, false><<<dim3(N2 / 128, Bsz / 128), 256, 0, stream>>>(A2, W2, nullptr, C2, N2);

    finalize<<<(Bsz * 64 + 255) / 256, 256, 0, stream>>>(C1, C2, h_re, h_im, (float*)d_out);
}

// Round 11
// 266.587 us; speedup vs baseline: 1.2959x; 1.0161x over previous
//
#include <hip/hip_runtime.h>
#include <stdint.h>

#define Bsz 16384
#define Hsz 256
#define K1 1024
#define N1 1536
#define K2 512
#define N2 512

typedef __bf16 bf16x8 __attribute__((ext_vector_type(8)));
typedef float f32x4 __attribute__((ext_vector_type(4)));
typedef unsigned short ushort8v __attribute__((ext_vector_type(8)));

__device__ __forceinline__ unsigned short f2bf(float f) {
    union { float f; unsigned int u; } v; v.f = f;
    unsigned int u = v.u;
    return (unsigned short)((u + 0x7fffu + ((u >> 16) & 1u)) >> 16);
}
__device__ __forceinline__ float bf2f(unsigned short s) {
    union { float f; unsigned int u; } v; v.u = ((unsigned int)s) << 16;
    return v.f;
}
__device__ __forceinline__ float sigm(float x) { return 1.0f / (1.0f + __expf(-x)); }
// tanh via fast exp: exact identity (e^2x-1)/(e^2x+1); clamp avoids inf/inf.
__device__ __forceinline__ float tanh_fast(float x) {
    float e = __expf(fminf(2.f * x, 30.f));
    return (e - 1.f) / (e + 1.f);
}

// ---------------- merged weight/bias prep (r10 layouts, verified) ----------------
// W1 [1536][1024] bf16: n in [0,768): re-out of gate g=n/256 (0=r,1=z,2=h1), j=n%256;
//   n in [768,1536): im-out. k<512: [x_re|h_re]; k>=512: [x_im|h_im].
// W2 [512][512] bf16: rh-part of Wh. bias1[1536] f32 (re: br-bi, im: br+bi).
__global__ void build_weights(
    const float* __restrict__ wr_re, const float* __restrict__ wr_im,
    const float* __restrict__ wz_re, const float* __restrict__ wz_im,
    const float* __restrict__ wh_re, const float* __restrict__ wh_im,
    const float* __restrict__ ur_re, const float* __restrict__ ur_im,
    const float* __restrict__ uz_re, const float* __restrict__ uz_im,
    const float* __restrict__ uh_re, const float* __restrict__ uh_im,
    const float* __restrict__ br_re, const float* __restrict__ br_im,
    const float* __restrict__ bz_re, const float* __restrict__ bz_im,
    const float* __restrict__ bh_re, const float* __restrict__ bh_im,
    unsigned short* __restrict__ W1, unsigned short* __restrict__ W2,
    float* __restrict__ bias1) {
    int idx = blockIdx.x * blockDim.x + threadIdx.x;
    if (idx < N1 * K1) {
        int n = idx / K1, k = idx % K1;
        int ng = n % 768;
        int g = ng / 256;
        int j = ng % 256;
        bool im_out = (n >= 768);
        bool second = (k >= 512);
        int kk = k & 511;
        const float *Wre, *Wim, *Ure, *Uim;
        if (g == 0)      { Wre = wr_re; Wim = wr_im; Ure = ur_re; Uim = ur_im; }
        else if (g == 1) { Wre = wz_re; Wim = wz_im; Ure = uz_re; Uim = uz_im; }
        else             { Wre = wh_re; Wim = wh_im; Ure = uh_re; Uim = uh_im; }
        float wre, wim;
        if (g < 2) {
            wre = Wre[j * 512 + kk];
            wim = Wim[j * 512 + kk];
            if (kk >= 256) { wre += Ure[j * 256 + kk - 256]; wim += Uim[j * 256 + kk - 256]; }
        } else {
            if (kk < 256) { wre = Wre[j * 512 + kk];       wim = Wim[j * 512 + kk]; }
            else          { wre = Ure[j * 256 + kk - 256]; wim = Uim[j * 256 + kk - 256]; }
        }
        float val = (!im_out) ? (second ? -wim : wre) : (second ? wre : wim);
        W1[idx] = f2bf(val);
        return;
    }
    int i2 = idx - N1 * K1;
    if (i2 < N2 * K2) {
        int n = i2 / K2, k = i2 % K2;
        int j = n & 255;
        bool im_out = (n >= 256);
        bool second = (k >= 256);
        int kk = k & 255;
        float wre = wh_re[j * 512 + 256 + kk];
        float wim = wh_im[j * 512 + 256 + kk];
        float val = (!im_out) ? (second ? -wim : wre) : (second ? wre : wim);
        W2[i2] = f2bf(val);
        return;
    }
    int i3 = i2 - N2 * K2;
    if (i3 < N1) {
        int ng = i3 % 768;
        int g = ng / 256;
        int j = ng % 256;
        const float* re = (g == 0) ? br_re : ((g == 1) ? bz_re : bh_re);
        const float* im = (g == 0) ? br_im : ((g == 1) ? bz_im : bh_im);
        bias1[i3] = (i3 < 768) ? (re[j] - im[j]) : (re[j] + im[j]);
    }
}

// ---------------- A builder: A = [x_re|h_re|x_im|h_im] bf16 [B,1024], 8 els/thread ----
__global__ __launch_bounds__(256)
void build_a(const float* __restrict__ xr, const float* __restrict__ hr,
             const float* __restrict__ xi, const float* __restrict__ hi,
             unsigned short* __restrict__ a) {
    int idx = blockIdx.x * blockDim.x + threadIdx.x;
    if (idx >= Bsz * K1 / 8) return;
    int t = idx * 8;
    int b = t >> 10;
    int k = t & 1023;
    const float* src;
    int off;
    if (k < 256)      { src = xr; off = b * 256 + k; }
    else if (k < 512) { src = hr; off = b * 256 + k - 256; }
    else if (k < 768) { src = xi; off = b * 256 + k - 512; }
    else              { src = hi; off = b * 256 + k - 768; }
    f32x4 v0 = *(const f32x4*)(src + off);
    f32x4 v1 = *(const f32x4*)(src + off + 4);
    ushort8v o;
#pragma unroll
    for (int q = 0; q < 4; q++) { o[q] = f2bf(v0[q]); o[q + 4] = f2bf(v1[q]); }
    *(ushort8v*)(a + t) = o;
}

// ---------------- bf16 GEMM (r2/r10 core VERBATIM; C store bf16) ----------------
// 128x128 tile, BK=32, 256 threads (4 waves 2x2), mfma_f32_16x16x32_bf16.
// Linear LDS (~6.3M conflict cycles) measured FASTER than all swizzled variants.
template<int K, bool HAS_BIAS>
__global__ __launch_bounds__(256)
void gemm_bt(const unsigned short* __restrict__ A,
             const unsigned short* __restrict__ Bm,
             const float* __restrict__ bias,
             unsigned short* __restrict__ C, int N) {
    __shared__ __align__(16) unsigned short sA[128 * 32];
    __shared__ __align__(16) unsigned short sB[128 * 32];
    const int tid  = threadIdx.x;
    const int lane = tid & 63;
    const int wid  = tid >> 6;
    const int rowA0 = blockIdx.y * 128;
    const int rowB0 = blockIdx.x * 128;
    const int wm = (wid >> 1) * 64;
    const int wn = (wid & 1) * 64;

    f32x4 acc[4][4];
#pragma unroll
    for (int i = 0; i < 4; i++)
#pragma unroll
        for (int j = 0; j < 4; j++) acc[i][j] = {0.f, 0.f, 0.f, 0.f};

    const int segRow   = lane >> 2;
    const int segChunk = lane & 3;
    const int fr = lane & 15;
    const int fc = lane >> 4;

    for (int k0 = 0; k0 < K; k0 += 32) {
        __syncthreads();
#pragma unroll
        for (int i = 0; i < 2; i++) {
            int s = wid + i * 4;
            int r = s * 16 + segRow;
            const unsigned short* gp = A + (size_t)(rowA0 + r) * K + k0 + segChunk * 8;
            unsigned short* lp = sA + s * 512 + lane * 8;
            __builtin_amdgcn_global_load_lds((const __attribute__((address_space(1))) void*)gp,
                                             (__attribute__((address_space(3))) void*)lp,
                                             16, 0, 0);
        }
#pragma unroll
        for (int i = 0; i < 2; i++) {
            int s = wid + i * 4;
            int r = s * 16 + segRow;
            const unsigned short* gp = Bm + (size_t)(rowB0 + r) * K + k0 + segChunk * 8;
            unsigned short* lp = sB + s * 512 + lane * 8;
            __builtin_amdgcn_global_load_lds((const __attribute__((address_space(1))) void*)gp,
                                             (__attribute__((address_space(3))) void*)lp,
                                             16, 0, 0);
        }
        __syncthreads();

        bf16x8 af[4], bfr[4];
#pragma unroll
        for (int m = 0; m < 4; m++) {
            int r = wm + m * 16 + fr;
            af[m] = *(const bf16x8*)(sA + r * 32 + fc * 8);
        }
#pragma unroll
        for (int n = 0; n < 4; n++) {
            int r = wn + n * 16 + fr;
            bfr[n] = *(const bf16x8*)(sB + r * 32 + fc * 8);
        }
#pragma unroll
        for (int m = 0; m < 4; m++)
#pragma unroll
            for (int n = 0; n < 4; n++)
                acc[m][n] = __builtin_amdgcn_mfma_f32_16x16x32_bf16(af[m], bfr[n], acc[m][n], 0, 0, 0);
    }

    const int crow = (lane >> 4) * 4;
    const int ccol = lane & 15;
#pragma unroll
    for (int m = 0; m < 4; m++) {
#pragma unroll
        for (int n = 0; n < 4; n++) {
            int gc = rowB0 + wn + n * 16 + ccol;
            float bv = HAS_BIAS ? bias[gc] : 0.f;
#pragma unroll
            for (int j = 0; j < 4; j++) {
                int gr = rowA0 + wm + m * 16 + crow + j;
                C[(size_t)gr * N + gc] = f2bf(acc[m][n][j] + bv);
            }
        }
    }
}

// ---------------- make_rh: 8 cols/thread, 6 independent 16B loads ----------------
__global__ __launch_bounds__(256)
void make_rh(const unsigned short* __restrict__ C1, const float* __restrict__ hr,
             const float* __restrict__ hi, unsigned short* __restrict__ A2) {
    int gid = blockIdx.x * blockDim.x + threadIdx.x;   // Bsz*32 total
    if (gid >= Bsz * 32) return;
    int b = gid >> 5;
    int j = (gid & 31) * 8;
    const unsigned short* c = C1 + (size_t)b * N1;
    ushort8v ar = *(const ushort8v*)(c + j);          // r_re preact
    ushort8v ai = *(const ushort8v*)(c + 768 + j);    // r_im preact
    f32x4 hr0 = *(const f32x4*)(hr + b * 256 + j);
    f32x4 hr1 = *(const f32x4*)(hr + b * 256 + j + 4);
    f32x4 hi0 = *(const f32x4*)(hi + b * 256 + j);
    f32x4 hi1 = *(const f32x4*)(hi + b * 256 + j + 4);
    ushort8v ore, oim;
#pragma unroll
    for (int t = 0; t < 4; t++) {
        float rr = sigm(bf2f(ar[t]));
        float ri = sigm(bf2f(ai[t]));
        ore[t] = f2bf(rr * hr0[t] - ri * hi0[t]);
        oim[t] = f2bf(rr * hi0[t] + ri * hr0[t]);
    }
#pragma unroll
    for (int t = 0; t < 4; t++) {
        float rr = sigm(bf2f(ar[t + 4]));
        float ri = sigm(bf2f(ai[t + 4]));
        ore[t + 4] = f2bf(rr * hr1[t] - ri * hi1[t]);
        oim[t + 4] = f2bf(rr * hi1[t] + ri * hr1[t]);
    }
    *(ushort8v*)(A2 + (size_t)b * 512 + j)       = ore;
    *(ushort8v*)(A2 + (size_t)b * 512 + 256 + j) = oim;
}

// ---------------- finalize: 8 cols/thread, 10 independent 16B loads ----------------
__global__ __launch_bounds__(256)
void finalize(const unsigned short* __restrict__ C1, const unsigned short* __restrict__ C2,
              const float* __restrict__ hr, const float* __restrict__ hi,
              float* __restrict__ out) {
    int gid = blockIdx.x * blockDim.x + threadIdx.x;   // Bsz*32 total
    if (gid >= Bsz * 32) return;
    int b = gid >> 5;
    int j = (gid & 31) * 8;
    const unsigned short* c1 = C1 + (size_t)b * N1;
    const unsigned short* c2 = C2 + (size_t)b * N2;
    ushort8v zr8  = *(const ushort8v*)(c1 + 256 + j);
    ushort8v zi8  = *(const ushort8v*)(c1 + 1024 + j);
    ushort8v h1r8 = *(const ushort8v*)(c1 + 512 + j);
    ushort8v h1i8 = *(const ushort8v*)(c1 + 1280 + j);
    ushort8v h2r8 = *(const ushort8v*)(c2 + j);
    ushort8v h2i8 = *(const ushort8v*)(c2 + 256 + j);
    f32x4 hr0 = *(const f32x4*)(hr + b * 256 + j);
    f32x4 hr1 = *(const f32x4*)(hr + b * 256 + j + 4);
    f32x4 hi0 = *(const f32x4*)(hi + b * 256 + j);
    f32x4 hi1 = *(const f32x4*)(hi + b * 256 + j + 4);
    f32x4 or0, or1, oi0, oi1;
#pragma unroll
    for (int t = 0; t < 4; t++) {
        float zr = sigm(bf2f(zr8[t]));
        float zi = sigm(bf2f(zi8[t]));
        float hhr = tanh_fast(bf2f(h1r8[t]) + bf2f(h2r8[t]));
        float hhi = tanh_fast(bf2f(h1i8[t]) + bf2f(h2i8[t]));
        or0[t] = (1.f - zr) * hr0[t] + zi * hi0[t] + zr * hhr - zi * hhi;
        oi0[t] = (1.f - zr) * hi0[t] - zi * hr0[t] + zr * hhi + zi * hhr;
    }
#pragma unroll
    for (int t = 0; t < 4; t++) {
        float zr = sigm(bf2f(zr8[t + 4]));
        float zi = sigm(bf2f(zi8[t + 4]));
        float hhr = tanh_fast(bf2f(h1r8[t + 4]) + bf2f(h2r8[t + 4]));
        float hhi = tanh_fast(bf2f(h1i8[t + 4]) + bf2f(h2i8[t + 4]));
        or1[t] = (1.f - zr) * hr1[t] + zi * hi1[t] + zr * hhr - zi * hhi;
        oi1[t] = (1.f - zr) * hi1[t] - zi * hr1[t] + zr * hhi + zi * hhr;
    }
    *(f32x4*)(out + (size_t)b * 256 + j)     = or0;
    *(f32x4*)(out + (size_t)b * 256 + j + 4) = or1;
    float* outi = out + (size_t)Bsz * 256;
    *(f32x4*)(outi + (size_t)b * 256 + j)     = oi0;
    *(f32x4*)(outi + (size_t)b * 256 + j + 4) = oi1;
}

extern "C" void kernel_launch(void* const* d_in, const int* in_sizes, int n_in,
                              void* d_out, int out_size, void* d_ws, size_t ws_size,
                              hipStream_t stream) {
    const float* x_re = (const float*)d_in[0];
    const float* x_im = (const float*)d_in[1];
    const float* h_re = (const float*)d_in[2];
    const float* h_im = (const float*)d_in[3];
    const float* wr_w_re = (const float*)d_in[4];
    const float* wr_w_im = (const float*)d_in[5];
    const float* wr_b_re = (const float*)d_in[6];
    const float* wr_b_im = (const float*)d_in[7];
    const float* wz_w_re = (const float*)d_in[8];
    const float* wz_w_im = (const float*)d_in[9];
    const float* wz_b_re = (const float*)d_in[10];
    const float* wz_b_im = (const float*)d_in[11];
    const float* wh_w_re = (const float*)d_in[12];
    const float* wh_w_im = (const float*)d_in[13];
    const float* wh_b_re = (const float*)d_in[14];
    const float* wh_b_im = (const float*)d_in[15];
    const float* ur_w_re = (const float*)d_in[16];
    const float* ur_w_im = (const float*)d_in[17];
    const float* uz_w_re = (const float*)d_in[18];
    const float* uz_w_im = (const float*)d_in[19];
    const float* uh_w_re = (const float*)d_in[20];
    const float* uh_w_im = (const float*)d_in[21];

    // ws layout. Total 121,116,672 B.
    char* ws = (char*)d_ws;
    unsigned short* W1    = (unsigned short*)(ws);                //  3,145,728 B
    unsigned short* W2    = (unsigned short*)(ws + 3145728);      //    524,288 B
    float*          bias1 = (float*)         (ws + 3670016);      //      6,144 B
    unsigned short* A_bf  = (unsigned short*)(ws + 3676160);      // 33,554,432 B
    unsigned short* A2    = (unsigned short*)(ws + 37230592);     // 16,777,216 B
    unsigned short* C1    = (unsigned short*)(ws + 54007808);     // 50,331,648 B (bf16)
    unsigned short* C2    = (unsigned short*)(ws + 104339456);    // 16,777,216 B (bf16)

    const int prep_elems = N1 * K1 + N2 * K2 + N1;
    build_weights<<<(prep_elems + 255) / 256, 256, 0, stream>>>(
        wr_w_re, wr_w_im, wz_w_re, wz_w_im, wh_w_re, wh_w_im,
        ur_w_re, ur_w_im, uz_w_re, uz_w_im, uh_w_re, uh_w_im,
        wr_b_re, wr_b_im, wz_b_re, wz_b_im, wh_b_re, wh_b_im,
        W1, W2, bias1);

    build_a<<<(Bsz * K1 / 8 + 255) / 256, 256, 0, stream>>>(x_re, h_re, x_im, h_im, A_bf);

    gemm_bt<K1, true><<<dim3(N1 / 128, Bsz / 128), 256, 0, stream>>>(A_bf, W1, bias1, C1, N1);

    make_rh<<<(Bsz * 32 + 255) / 256, 256, 0, stream>>>(C1, h_re, h_im, A2);

    gemm_bt<K2, false><<<dim3(N2 / 128, Bsz / 128), 256, 0, stream>>>(A2, W2, nullptr, C2, N2);

    finalize<<<(Bsz * 32 + 255) / 256, 256, 0, stream>>>(C1, C2, h_re, h_im, (float*)d_out);
}